// Round 10
// baseline (373.188 us; speedup 1.0000x reference)
//
#include <hip/hip_runtime.h>
#include <hip/hip_fp16.h>

#define NROW 32768
#define DIM  256
#define NC   8192
#define CAP  16384                     // max rescued rows (expect ~2500)
#define MARGINF 0.25f                  // flag threshold: not-flagged => true cheap gap >= 0.125
#define BIAS 512.0f                    // cheap-score bias: guarantees all cheap scores negative
#define AST 576                        // A' row: [hi 256 | ones 32 | lo 256 | pad 32] halves
#define BST 576                        // B' row: [hi 256 | ch 32   | lo 256 | pad 32] halves
#define LOSS_SCALE (1.0f / 8388608.0f)

typedef __attribute__((ext_vector_type(8))) _Float16 half8;
typedef __attribute__((ext_vector_type(4))) _Float16 half4;
typedef __attribute__((ext_vector_type(4))) float   floatx4;
typedef const __attribute__((address_space(1))) void* gas_p;
typedef __attribute__((address_space(3))) void*       las_p;

static __device__ __forceinline__ unsigned short f2hb(float f) {
    _Float16 h = (_Float16)f;
    unsigned short u;
    __builtin_memcpy(&u, &h, 2);
    return u;
}
static __device__ __forceinline__ unsigned umin_(unsigned a, unsigned b) { return a < b ? a : b; }
static __device__ __forceinline__ unsigned umax_(unsigned a, unsigned b) { return a > b ? a : b; }

// ======================= prep kernels (fast path) =======================

__global__ void prep_a_k(const float* __restrict__ x, unsigned short* __restrict__ Ah,
                         float* __restrict__ norms) {
    int row  = blockIdx.x * 4 + (threadIdx.x >> 6);
    int lane = threadIdx.x & 63;
    const float4 v = ((const float4*)(x + (size_t)row * DIM))[lane];
    float s = v.x * v.x + v.y * v.y + v.z * v.z + v.w * v.w;
#pragma unroll
    for (int off = 32; off; off >>= 1) s += __shfl_down(s, off, 64);
    if (lane == 0) norms[row] = s;
    ushort4 hi4 = make_ushort4(f2hb(v.x), f2hb(v.y), f2hb(v.z), f2hb(v.w));
    ushort4 lo4 = make_ushort4(f2hb(v.x - (float)(_Float16)v.x),
                               f2hb(v.y - (float)(_Float16)v.y),
                               f2hb(v.z - (float)(_Float16)v.z),
                               f2hb(v.w - (float)(_Float16)v.w));
    unsigned short* rp = Ah + (size_t)row * AST;
    *(ushort4*)(rp + lane * 4)       = hi4;
    *(ushort4*)(rp + 288 + lane * 4) = lo4;
    if (lane < 8) {                    // legacy ones block (unused by cheap)
        ushort4 ob = make_ushort4(0, 0, 0, 0);
        if (lane == 0) { ob.x = 0x3C00; ob.y = 0x3C00; }
        *(ushort4*)(rp + 256 + lane * 4) = ob;
    }
}

__global__ void code_norms_k(const float* __restrict__ e, unsigned short* __restrict__ Bh,
                             float* __restrict__ cHalf) {
    int j = blockIdx.x * 256 + threadIdx.x;
    float s = 0.f;
    for (int d = 0; d < DIM; ++d) { float v = e[(size_t)d * NC + j]; s += v * v; }
    cHalf[j] = 0.5f * s;
    float t = -0.5f * s - BIAS;        // legacy ch block (unused by cheap)
    unsigned short hi = f2hb(t);
    _Float16 hf; __builtin_memcpy(&hf, &hi, 2);
    unsigned short lo = f2hb(t - (float)hf);
    unsigned short* p = Bh + (size_t)j * BST + 256;
    p[0] = hi; p[1] = lo;
    for (int k2 = 2; k2 < 32; ++k2) p[k2] = 0;
}

__global__ void prep_b_k(const float* __restrict__ e, unsigned short* __restrict__ Bh) {
    __shared__ float t[32][33];
    int jb = blockIdx.x * 32, db = blockIdx.y * 32;
#pragma unroll
    for (int i = 0; i < 4; ++i)
        t[threadIdx.y + i * 8][threadIdx.x] =
            e[(size_t)(db + threadIdx.y + i * 8) * NC + jb + threadIdx.x];
    __syncthreads();
#pragma unroll
    for (int i = 0; i < 4; ++i) {
        int j = jb + threadIdx.y + i * 8;
        int d = db + threadIdx.x;
        float val = t[threadIdx.x][threadIdx.y + i * 8];
        Bh[(size_t)j * BST + d]       = f2hb(val);
        Bh[(size_t)j * BST + 288 + d] = f2hb(val - (float)(_Float16)val);
    }
}

// ======================= R18 cheap kernel: BARRIER-FREE main loop =======================
// R11..R17 post-mortem: every waitcnt/order/stagger variant left body time ~= SUM(MFMA 620,
// LDS ~900) because the per-body s_barrier re-synchronizes all 8 waves 64x -> CU-wide
// phase lockstep (LDS pipe idle during the MFMA burst and vice versa). The barrier exists
// only because B staging was COOPERATIVE (waves read other waves' staged data).
// R18: each wave stages ITS OWN 64 B-columns into a PRIVATE 3-deep LDS ring -> all main-
// loop synchronization is per-wave vmcnt/lgkmcnt; ZERO barriers in 64 bodies. Waves drift
// freely and the pipes co-schedule across waves (m114 regime).
//   - Cost: B staged 2x (row-group partners duplicate their wc panel): 32KB/body from L2
//     (B is 9.4 MB, L2-resident; HBM FETCH unchanged). Coalescing preserved: stage instr q
//     maps 4 lanes per column -> 16 x 64B lines per instruction.
//   - LDS 136KB: Asl[4] 32KB (A chunks 4-7; chunks 0-3 staged through the ring area as
//     prologue scratch, then hoisted to ar[4][4]) + Bw[8][3][2048h] 96KB + chl 8KB.
//   - Per-wave B layout: addr(col,p) = col*64B + p*16B, storing k-granule g at position
//     p = g ^ s(col), s(c)=(c&3)^((c>>2)&3). Stage lane map: col = q*16 + (lane>>2),
//     p = lane&3 -> s is LANE-CONSTANT (q*4 and cf*4 vanish mod 4) -> one g per lane.
//     Frag read: bf[cf] at (cf*16+l15)*32 + ((lq^sR)*8) halves, sR=(l15&3)^((l15>>2)&3).
//     Conflicts: 2-way max (free, m136).
//   - Body t: vmcnt(8) [chunk t staged 3 bodies ago - no stall] -> frag reads(t) ->
//     lgkmcnt(0) [reads drained] -> stage(t+3) into the SAME slot (just freed) -> 16 MFMA
//     (operands arrived) -> epilogue at c==7. Slot is a cycling register (LDS addressing
//     may be runtime; no register-array indexing - rule #20 safe).
//   - All hazards wave-local: ring slot rewritten immediately after this wave's lgkmcnt(0);
//     A/chl are read-only after the 2 prologue barriers. Tail bodies stage wrap-around
//     dummies (valid addresses, never read); final __syncthreads drains them.

__global__ __launch_bounds__(512, 2) void vq_cheap_k(
    const unsigned short* __restrict__ Ah, const unsigned short* __restrict__ Bh,
    const float* __restrict__ cHalf,
    float* __restrict__ pv, int* __restrict__ pj, float* __restrict__ psv)
{
    __shared__ __align__(16) _Float16 Asl[4][4096];   // 32 KB: A chunks 4-7
    __shared__ __align__(16) _Float16 Bw[8][3][2048]; // 96 KB: per-wave 3-deep B rings
    __shared__ float chl[2048];                       //  8 KB

    const int tid  = threadIdx.x;
    const int js   = blockIdx.x & 3;
    const int rb   = blockIdx.x >> 2;
    const int row0 = rb * 128, col0 = js * 2048;
    const int lane = tid & 63, l15 = lane & 15, lq = lane >> 4;
    const int wave = tid >> 6;                 // 0..7
    const int wr = (wave >> 2) * 64;           // 0 / 64
    const int wc = (wave & 3) * 64;            // 0 / 64 / 128 / 192
    const int sr = tid >> 2;                   // A staging row 0..127
    const int ks = (((tid & 3) ^ (sr & 3) ^ ((sr >> 2) & 3))) * 8;  // A swizzled k-offset

    // ---- B stage lane mapping (per-instr q: col = q*16 + colq, position = pq) ----
    const int colq = lane >> 2;                // 0..15
    const int pq   = lane & 3;                 // granule position
    const int sgS  = (colq & 3) ^ ((colq >> 2) & 3);  // s(col) is q-invariant
    const int gS   = (pq ^ sgS) * 8;           // global k-granule offset (halves)
    // ---- B frag read offsets (halves): s(col) is cf-invariant ----
    const int sR   = (l15 & 3) ^ ((l15 >> 2) & 3);
    const int roB  = l15 * 32 + ((lq ^ sR) * 8);      // + cf*512

    // ---- chl first ----
    {
        float4 a = ((const float4*)(cHalf + col0))[tid];
        a.x += BIAS; a.y += BIAS; a.z += BIAS; a.w += BIAS;
        ((float4*)chl)[tid] = a;
    }

    // ---- A: chunks 4-7 -> Asl; chunks 0-3 -> scratch in the Bw region ----
    const unsigned short* Abase = Ah + (size_t)(row0 + sr) * AST + ks;
    _Float16* Ascr = &Bw[0][0][0];             // 32 KB scratch (overwritten after barrier 2)
#pragma unroll
    for (int c = 0; c < 4; ++c)
        __builtin_amdgcn_global_load_lds((gas_p)(Abase + (c + 4) * 32), (las_p)&Asl[c][tid * 8], 16, 0, 0);
#pragma unroll
    for (int c = 0; c < 4; ++c)
        __builtin_amdgcn_global_load_lds((gas_p)(Abase + c * 32), (las_p)&Ascr[c * 4096 + tid * 8], 16, 0, 0);

    asm volatile("s_waitcnt vmcnt(0) lgkmcnt(0)" ::: "memory");
    __builtin_amdgcn_s_barrier();              // all A staged + chl written

    // ---- A chunks 0-3 -> registers (64 VGPR) ----
    half8 ar[4][4];
#pragma unroll
    for (int c = 0; c < 4; ++c)
#pragma unroll
        for (int rf = 0; rf < 4; ++rf) {
            const int m = wr + rf * 16 + l15;
            const int g = lq ^ (m & 3) ^ ((m >> 2) & 3);
            ar[c][rf] = *(const half8*)&Ascr[c * 4096 + m * 32 + g * 8];
        }
    asm volatile("s_waitcnt lgkmcnt(0)" ::: "memory");
    __builtin_amdgcn_s_barrier();              // all waves done with scratch; rings now free

    // ---- per-wave B staging: 4 x global_load_lds per chunk (own 64 cols) ----
    const unsigned short* Bbase = Bh + (size_t)(col0 + wc + colq) * BST + gS;  // + q*16*BST + jt*256*BST + c*32
#define STAGEB(JT_, C_, SLOT_)                                                                \
    do {                                                                                      \
        const unsigned short* b0_ = Bbase + (size_t)(JT_) * (256 * BST) + (C_) * 32;          \
        _Float16* d0_ = &Bw[wave][(SLOT_)][lane * 8];                                         \
        __builtin_amdgcn_global_load_lds((gas_p)(b0_),                (las_p)(d0_),          16, 0, 0); \
        __builtin_amdgcn_global_load_lds((gas_p)(b0_ + 16 * BST),     (las_p)(d0_ + 512),    16, 0, 0); \
        __builtin_amdgcn_global_load_lds((gas_p)(b0_ + 32 * BST),     (las_p)(d0_ + 1024),   16, 0, 0); \
        __builtin_amdgcn_global_load_lds((gas_p)(b0_ + 48 * BST),     (las_p)(d0_ + 1536),   16, 0, 0); \
    } while (0)

    // prime the private ring: chunks 0,1,2 -> slots 0,1,2
    STAGEB(0, 0, 0);
    STAGEB(0, 1, 1);
    STAGEB(0, 2, 2);

    unsigned k1[16], k2[16];
#pragma unroll
    for (int s = 0; s < 16; ++s) { k1[s] = 0xFFFFFFFFu; k2[s] = 0xFFFFFFFFu; }

    const floatx4 fzero = {0.0f, 0.0f, 0.0f, 0.0f};
    floatx4 acc[4][4];
#pragma unroll
    for (int rf = 0; rf < 4; ++rf)
#pragma unroll
        for (int cf = 0; cf < 4; ++cf) acc[rf][cf] = fzero;

    half8 af[4], bf[4];
    int slot = 0;                              // ring slot of the current chunk (t % 3)

    for (int jt = 0; jt < 8; ++jt) {
#pragma unroll
        for (int c = 0; c < 8; ++c) {
            // chunk t's 4 stage-loads retired (12 outstanding -> keep t+1, t+2's 8)
            asm volatile("s_waitcnt vmcnt(8)" ::: "memory");

            // frag reads for chunk t (own ring; A from Asl for chunks 4-7)
            if (c >= 4) {
#pragma unroll
                for (int rf = 0; rf < 4; ++rf) {
                    const int m = wr + rf * 16 + l15;
                    const int g = lq ^ (m & 3) ^ ((m >> 2) & 3);
                    af[rf] = *(const half8*)&Asl[c - 4][m * 32 + g * 8];
                }
            }
#pragma unroll
            for (int cf = 0; cf < 4; ++cf)
                bf[cf] = *(const half8*)&Bw[wave][slot][cf * 512 + roB];

            // drain own reads, then recycle this slot for chunk t+3
            asm volatile("s_waitcnt lgkmcnt(0)" ::: "memory");
            __builtin_amdgcn_sched_barrier(0);
            {
                const int T   = jt * 8 + c + 3;
                const int jtn = (T >> 3) & 7;  // wraps harmlessly at the tail (dummy stages)
                const int cn  = T & 7;
                STAGEB(jtn, cn, slot);
            }

            // MFMA chunk t (operands in registers)
            __builtin_amdgcn_s_setprio(1);
            if (c < 4) {
#pragma unroll
                for (int rf = 0; rf < 4; ++rf)
#pragma unroll
                    for (int cf = 0; cf < 4; ++cf)
                        acc[rf][cf] = __builtin_amdgcn_mfma_f32_16x16x32_f16(
                            ar[c][rf], bf[cf], acc[rf][cf], 0, 0, 0);
            } else {
#pragma unroll
                for (int rf = 0; rf < 4; ++rf)
#pragma unroll
                    for (int cf = 0; cf < 4; ++cf)
                        acc[rf][cf] = __builtin_amdgcn_mfma_f32_16x16x32_f16(
                            af[rf], bf[cf], acc[rf][cf], 0, 0, 0);
            }
            __builtin_amdgcn_s_setprio(0);

            if (c == 7) {
                // ---- per-jt epilogue (no barrier anywhere near; chl is read-only) ----
#pragma unroll
                for (int cf = 0; cf < 4; ++cf) {
                    const unsigned colb = (unsigned)(jt * 256 + wc + cf * 16 + l15); // 11-bit local col
                    const float ch = chl[colb];
#pragma unroll
                    for (int rf = 0; rf < 4; ++rf)
#pragma unroll
                        for (int r = 0; r < 4; ++r) {
                            float s = acc[rf][cf][r] - ch;
                            unsigned key = (__float_as_uint(s) & 0xFFFFF800u) | colb;
                            int slot2 = rf * 4 + r;
                            unsigned t = umax_(key, k1[slot2]);
                            k1[slot2] = umin_(k1[slot2], key);
                            k2[slot2] = umin_(k2[slot2], t);
                        }
                }
#pragma unroll
                for (int rf = 0; rf < 4; ++rf)
#pragma unroll
                    for (int cf = 0; cf < 4; ++cf) acc[rf][cf] = fzero;
            }

            slot = (slot == 2) ? 0 : slot + 1;
        }
    }
#undef STAGEB

    // ---- cross-lane merge over the 16 l15-lanes of each row-group ----
#pragma unroll
    for (int st = 1; st < 16; st <<= 1) {
#pragma unroll
        for (int s = 0; s < 16; ++s) {
            unsigned o1 = (unsigned)__shfl_xor((int)k1[s], st, 64);
            unsigned o2 = (unsigned)__shfl_xor((int)k2[s], st, 64);
            unsigned t = umax_(k1[s], o1);
            k1[s] = umin_(k1[s], o1);
            k2[s] = umin_(umin_(k2[s], o2), t);
        }
    }

    // ---- merge the four column-group waves per row through LDS ----
    __syncthreads();                            // drains the 12 dummy tail stages too
    unsigned* mk1 = (unsigned*)&Asl[0][0];      // [128 rows][4 col-groups]
    unsigned* mk2 = (unsigned*)&Asl[1][0];
    if (l15 == 0) {
#pragma unroll
        for (int rf = 0; rf < 4; ++rf)
#pragma unroll
            for (int r = 0; r < 4; ++r) {
                int rloc = wr + rf * 16 + lq * 4 + r;
                int s2 = rf * 4 + r;
                mk1[rloc * 4 + (wave & 3)] = k1[s2];
                mk2[rloc * 4 + (wave & 3)] = k2[s2];
            }
    }
    __syncthreads();
    if (tid < 128) {
        unsigned a0 = mk1[tid * 4], a1 = mk1[tid * 4 + 1], a2 = mk1[tid * 4 + 2], a3 = mk1[tid * 4 + 3];
        unsigned x = umin_(a0, a1), y = umax_(a0, a1);
        unsigned z = umin_(a2, a3), w = umax_(a2, a3);
        unsigned m1  = umin_(x, z);
        unsigned sm1 = umin_(umax_(x, z), umin_(y, w));            // 2nd-best of the four bests
        unsigned s0 = mk2[tid * 4], s1 = mk2[tid * 4 + 1], s2 = mk2[tid * 4 + 2], s3 = mk2[tid * 4 + 3];
        unsigned m2 = umin_(umin_(umin_(s0, s1), umin_(s2, s3)), sm1);
        pv[(size_t)js * NROW + row0 + tid]  = __uint_as_float(m1 & 0xFFFFF800u);
        pj[(size_t)js * NROW + row0 + tid]  = (int)(m1 & 2047u) + js * 2048;
        psv[(size_t)js * NROW + row0 + tid] = __uint_as_float(m2 & 0xFFFFF800u);
    }
}

// ======================= rescue GEMM (R8-verified, unchanged) =======================

template<bool RESCUE>
static __device__ __forceinline__ void chunk_off(int c, int& ac, int& bc) {
    if constexpr (RESCUE) {
        if (c < 8)       { ac = c * 32;              bc = c * 32; }
        else if (c < 16) { ac = (c - 8) * 32;        bc = 288 + (c - 8) * 32; }
        else             { ac = 288 + (c - 16) * 32; bc = (c - 16) * 32; }
    } else {
        ac = c * 32; bc = c * 32;
    }
}

template<int CHUNKS, int JT, int JSB, bool RESCUE>
__global__ __launch_bounds__(256, 2) void vq_gemm_k(
    const unsigned short* __restrict__ Ah, const unsigned short* __restrict__ Bh,
    const float* __restrict__ cHalf,
    float* __restrict__ pv, int* __restrict__ pj, float* __restrict__ psv,
    const int* __restrict__ list, const int* __restrict__ cnt)
{
    __shared__ __align__(16) _Float16 As[2][4096];
    __shared__ __align__(16) _Float16 Bs[2][4096];

    const int tid  = threadIdx.x;
    const int js   = blockIdx.x & ((1 << JSB) - 1);
    const int rb   = blockIdx.x >> JSB;
    const int row0 = rb * 128, col0 = js * (JT * 128);
    const int lane = tid & 63, l15 = lane & 15, lq = lane >> 4;
    const int wave = tid >> 6;
    const int wrow = (wave >> 1) * 64, wcol = (wave & 1) * 64;
    const int sr = tid >> 2, sp = (tid & 3) * 8;

    int nact = 0;
    if constexpr (RESCUE) {
        nact = *cnt;
        if (row0 >= nact) return;
    }

    const unsigned short *Abase0, *Abase1;
    if constexpr (RESCUE) {
        int i0 = row0 + sr, i1 = i0 + 64;
        int r0 = (i0 < nact) ? list[i0] : 0;
        int r1 = (i1 < nact) ? list[i1] : 0;
        Abase0 = Ah + (size_t)r0 * AST + sp;
        Abase1 = Ah + (size_t)r1 * AST + sp;
    } else {
        Abase0 = Ah + (size_t)(row0 + sr) * AST + sp;
        Abase1 = Abase0 + 64 * AST;
    }

    unsigned k1[16], k2[16];
    float bvf[16]; int bjf[16];
#pragma unroll
    for (int s = 0; s < 16; ++s) {
        k1[s] = 0xFFFFFFFFu; k2[s] = 0xFFFFFFFFu;
        bvf[s] = -3.4e38f; bjf[s] = 0;
    }

    const floatx4 fzero = {0.0f, 0.0f, 0.0f, 0.0f};
    floatx4 acc[4][4];
#pragma unroll
    for (int rf = 0; rf < 4; ++rf)
#pragma unroll
        for (int cf = 0; cf < 4; ++cf) acc[rf][cf] = fzero;

    const unsigned short* Bb = Bh + (size_t)(col0 + sr) * BST + sp;

#define LOAD4(AC, BC, BUF, BBASE)                                                            \
    do {                                                                                     \
        _Float16* la_ = &As[(BUF)][tid * 8];                                                 \
        _Float16* lb_ = &Bs[(BUF)][tid * 8];                                                 \
        __builtin_amdgcn_global_load_lds((gas_p)(Abase0 + (AC)),            (las_p)la_,          16, 0, 0); \
        __builtin_amdgcn_global_load_lds((gas_p)(Abase1 + (AC)),            (las_p)(la_ + 2048), 16, 0, 0); \
        __builtin_amdgcn_global_load_lds((gas_p)((BBASE) + (BC)),           (las_p)lb_,          16, 0, 0); \
        __builtin_amdgcn_global_load_lds((gas_p)((BBASE) + 64 * BST + (BC)),(las_p)(lb_ + 2048), 16, 0, 0); \
    } while (0)

    LOAD4(0, 0, 0, Bb);

    for (int jt = 0; jt < JT; ++jt) {
        const int p = (CHUNKS & 1) ? (jt & 1) : 0;
#pragma unroll
        for (int c = 0; c < CHUNKS; ++c) {
            const int buf = (c & 1) ^ p;
            __syncthreads();
            if (c + 1 < CHUNKS) {
                int an, bn;
                chunk_off<RESCUE>(c + 1, an, bn);
                LOAD4(an, bn, buf ^ 1, Bb);
            } else if (jt + 1 < JT) {
                LOAD4(0, 0, buf ^ 1, Bb + 128 * BST);
            }

            half8 af[4], bf[4];
#pragma unroll
            for (int rf = 0; rf < 4; ++rf)
                af[rf] = *(const half8*)&As[buf][(wrow + rf * 16 + l15) * 32 + lq * 8];
#pragma unroll
            for (int cf = 0; cf < 4; ++cf)
                bf[cf] = *(const half8*)&Bs[buf][(wcol + cf * 16 + l15) * 32 + lq * 8];
#pragma unroll
            for (int rf = 0; rf < 4; ++rf)
#pragma unroll
                for (int cf = 0; cf < 4; ++cf)
                    acc[rf][cf] = __builtin_amdgcn_mfma_f32_16x16x32_f16(
                        af[rf], bf[cf], acc[rf][cf], 0, 0, 0);

            if (c == CHUNKS - 1) {
                if constexpr (RESCUE) {
                    const int colbase = col0 + jt * 128 + wcol;
#pragma unroll
                    for (int cf = 0; cf < 4; ++cf) {
                        const int col = colbase + cf * 16 + l15;
                        const float ch = cHalf[col];
#pragma unroll
                        for (int rf = 0; rf < 4; ++rf)
#pragma unroll
                            for (int r = 0; r < 4; ++r) {
                                float s = acc[rf][cf][r] - ch;
                                int slot = rf * 4 + r;
                                if (s > bvf[slot]) { bvf[slot] = s; bjf[slot] = col; }
                            }
                    }
                } else {
                    const unsigned colloc = (unsigned)(jt * 128 + wcol);
#pragma unroll
                    for (int cf = 0; cf < 4; ++cf) {
                        const unsigned colb = colloc + cf * 16 + l15;
#pragma unroll
                        for (int rf = 0; rf < 4; ++rf)
#pragma unroll
                            for (int r = 0; r < 4; ++r) {
                                unsigned key = (__float_as_uint(acc[rf][cf][r]) & 0xFFFFF800u) | colb;
                                int slot = rf * 4 + r;
                                unsigned t = umax_(key, k1[slot]);
                                k1[slot] = umin_(k1[slot], key);
                                k2[slot] = umin_(k2[slot], t);
                            }
                    }
                }
#pragma unroll
                for (int rf = 0; rf < 4; ++rf)
#pragma unroll
                    for (int cf = 0; cf < 4; ++cf) acc[rf][cf] = fzero;
            }
        }
        Bb += 128 * BST;
    }
#undef LOAD4

#pragma unroll
    for (int st = 1; st < 16; st <<= 1) {
#pragma unroll
        for (int s = 0; s < 16; ++s) {
            if constexpr (RESCUE) {
                float v2 = __shfl_xor(bvf[s], st, 64);
                int   j2 = __shfl_xor(bjf[s], st, 64);
                if (v2 > bvf[s] || (v2 == bvf[s] && j2 < bjf[s])) { bvf[s] = v2; bjf[s] = j2; }
            } else {
                unsigned o1 = (unsigned)__shfl_xor((int)k1[s], st, 64);
                unsigned o2 = (unsigned)__shfl_xor((int)k2[s], st, 64);
                unsigned t = umax_(k1[s], o1);
                k1[s] = umin_(k1[s], o1);
                k2[s] = umin_(umin_(k2[s], o2), t);
            }
        }
    }

    __syncthreads();
    if constexpr (RESCUE) {
        float* mv = (float*)&As[0][0];
        int*   mj = (int*)&Bs[0][0];
        if (l15 == 0) {
#pragma unroll
            for (int rf = 0; rf < 4; ++rf)
#pragma unroll
                for (int r = 0; r < 4; ++r) {
                    int rloc = wrow + rf * 16 + lq * 4 + r;
                    int slot = rf * 4 + r;
                    mv[rloc * 2 + (wave & 1)] = bvf[slot];
                    mj[rloc * 2 + (wave & 1)] = bjf[slot];
                }
        }
        __syncthreads();
        if (tid < 128) {
            float v0 = mv[tid * 2], v1 = mv[tid * 2 + 1];
            int   j0 = mj[tid * 2], j1 = mj[tid * 2 + 1];
            bool take1 = (v1 > v0) || (v1 == v0 && j1 < j0);
            pv[(size_t)js * CAP + row0 + tid] = take1 ? v1 : v0;
            pj[(size_t)js * CAP + row0 + tid] = take1 ? j1 : j0;
        }
    } else {
        unsigned* mk1 = (unsigned*)&As[0][0];
        unsigned* mk2 = (unsigned*)&Bs[0][0];
        if (l15 == 0) {
#pragma unroll
            for (int rf = 0; rf < 4; ++rf)
#pragma unroll
                for (int r = 0; r < 4; ++r) {
                    int rloc = wrow + rf * 16 + lq * 4 + r;
                    int slot = rf * 4 + r;
                    mk1[rloc * 2 + (wave & 1)] = k1[slot];
                    mk2[rloc * 2 + (wave & 1)] = k2[slot];
                }
        }
        __syncthreads();
        if (tid < 128) {
            unsigned a1 = mk1[tid * 2], b1 = mk1[tid * 2 + 1];
            unsigned a2 = mk2[tid * 2], b2 = mk2[tid * 2 + 1];
            unsigned m1 = umin_(a1, b1);
            unsigned m2 = umin_(umin_(a2, b2), umax_(a1, b1));
            pv[(size_t)js * NROW + row0 + tid] = __uint_as_float(m1 & 0xFFFFF800u);
            pj[(size_t)js * NROW + row0 + tid] = (int)(m1 & 2047u) + js * (JT * 128);
            psv[(size_t)js * NROW + row0 + tid] = __uint_as_float(m2 & 0xFFFFF800u);
        }
    }
}

// ======================= cheap reduce: merge splits, flag, gather =======================

__global__ void vq_reduce_k(const float* __restrict__ pv, const int* __restrict__ pj,
                            const float* __restrict__ psv,
                            const float* __restrict__ norms, const unsigned short* __restrict__ Bh,
                            float* __restrict__ qout, float* __restrict__ iout,
                            float* __restrict__ lout, int* __restrict__ list,
                            int* __restrict__ cnt)
{
    __shared__ int jbuf[64];
    const int row0 = blockIdx.x * 64;
    const int tid = threadIdx.x;
    if (tid < 64) {
        int row = row0 + tid;
        float bv = pv[row]; int bj = pj[row]; float sv = psv[row];
#pragma unroll
        for (int s = 1; s < 4; ++s) {
            float v = pv[(size_t)s * NROW + row];
            int   j = pj[(size_t)s * NROW + row];
            float s2 = psv[(size_t)s * NROW + row];
            bool better = (v > bv) || (v == bv && j < bj);
            float loseBest = better ? bv : v;
            sv = fmaxf(fmaxf(sv, s2), loseBest);
            if (better) { bv = v; bj = j; }
        }
        bool flagged = (bv - sv) < MARGINF;
        if (flagged) {
            int idx = atomicAdd(cnt, 1);
            if (idx < CAP) {
                list[idx] = row;
                jbuf[tid] = -1;
            } else {
                flagged = false;
            }
        }
        float rl = 0.f;
        if (!flagged) {
            iout[row] = (float)bj;
            jbuf[tid] = bj;
            rl = norms[row] - 2.0f * (bv + BIAS - 0.0625f);
        }
#pragma unroll
        for (int off = 32; off; off >>= 1) rl += __shfl_down(rl, off, 64);
        if (tid == 0) atomicAdd(lout, rl * LOSS_SCALE);
    }
    __syncthreads();
    const int lane = tid & 63;
    for (int r = tid >> 6; r < 64; r += 4) {
        int j = jbuf[r];
        if (j >= 0) {
            const _Float16* bp = (const _Float16*)Bh + (size_t)j * BST + lane * 4;
            half4 h = *(const half4*)bp;
            half4 l = *(const half4*)(bp + 288);
            float4 v;
            v.x = (float)h[0] + (float)l[0];
            v.y = (float)h[1] + (float)l[1];
            v.z = (float)h[2] + (float)l[2];
            v.w = (float)h[3] + (float)l[3];
            *(float4*)&qout[(size_t)(row0 + r) * DIM + lane * 4] = v;
        }
    }
}

// ======================= rescue reduce: merge 32 splits, finalize =======================

__global__ void vq_reduce2_k(const float* __restrict__ pv2, const int* __restrict__ pj2,
                             const int* __restrict__ list, const int* __restrict__ cnt,
                             const float* __restrict__ norms, const unsigned short* __restrict__ Bh,
                             float* __restrict__ qout, float* __restrict__ iout,
                             float* __restrict__ lout)
{
    __shared__ int rbuf[64], jb2[64];
    const int n = *cnt < CAP ? *cnt : CAP;
    const int i0 = blockIdx.x * 64;
    if (i0 >= n) return;
    const int tid = threadIdx.x;
    if (tid < 64) {
        int i = i0 + tid;
        float rl = 0.f;
        if (i < n) {
            float bv = pv2[i]; int bj = pj2[i];
#pragma unroll 4
            for (int s = 1; s < 32; ++s) {
                float v = pv2[(size_t)s * CAP + i];
                int   j = pj2[(size_t)s * CAP + i];
                if (v > bv || (v == bv && j < bj)) { bv = v; bj = j; }
            }
            int row = list[i];
            iout[row] = (float)bj;
            rbuf[tid] = row;
            jb2[tid]  = bj;
            rl = norms[row] - 2.0f * bv;
        } else {
            rbuf[tid] = -1;
        }
#pragma unroll
        for (int off = 32; off; off >>= 1) rl += __shfl_down(rl, off, 64);
        if (tid == 0) atomicAdd(lout, rl * LOSS_SCALE);
    }
    __syncthreads();
    const int lane = tid & 63;
    for (int r = tid >> 6; r < 64; r += 4) {
        int row = rbuf[r];
        if (row >= 0) {
            const _Float16* bp = (const _Float16*)Bh + (size_t)jb2[r] * BST + lane * 4;
            half4 h = *(const half4*)bp;
            half4 l = *(const half4*)(bp + 288);
            float4 v;
            v.x = (float)h[0] + (float)l[0];
            v.y = (float)h[1] + (float)l[1];
            v.z = (float)h[2] + (float)l[2];
            v.w = (float)h[3] + (float)l[3];
            *(float4*)&qout[(size_t)row * DIM + lane * 4] = v;
        }
    }
}

// ======================= fallback fp32 path (round-1, known-good) =======================

__global__ void transpose_k(const float* __restrict__ e, float* __restrict__ eT) {
    __shared__ float t[32][33];
    int jb = blockIdx.x * 32, db = blockIdx.y * 32;
#pragma unroll
    for (int i = 0; i < 4; ++i)
        t[threadIdx.y + i * 8][threadIdx.x] =
            e[(size_t)(db + threadIdx.y + i * 8) * NC + jb + threadIdx.x];
    __syncthreads();
#pragma unroll
    for (int i = 0; i < 4; ++i)
        eT[(size_t)(jb + threadIdx.y + i * 8) * DIM + db + threadIdx.x] =
            t[threadIdx.x][threadIdx.y + i * 8];
}

__global__ void row_norms_k(const float* __restrict__ x, float* __restrict__ norms) {
    int row  = blockIdx.x * 4 + (threadIdx.x >> 6);
    int lane = threadIdx.x & 63;
    const float4 v = ((const float4*)(x + (size_t)row * DIM))[lane];
    float s = v.x * v.x + v.y * v.y + v.z * v.z + v.w * v.w;
#pragma unroll
    for (int off = 32; off; off >>= 1) s += __shfl_down(s, off, 64);
    if (lane == 0) norms[row] = s;
}

__global__ void code_norms_fb_k(const float* __restrict__ e, float* __restrict__ cHalf) {
    int j = blockIdx.x * 256 + threadIdx.x;
    float s = 0.f;
    for (int d = 0; d < DIM; ++d) { float v = e[(size_t)d * NC + j]; s += v * v; }
    cHalf[j] = 0.5f * s;
}

__global__ __launch_bounds__(256, 4) void vq_main_k(
    const float* __restrict__ x, const float* __restrict__ e,
    const float* __restrict__ eT, const float* __restrict__ norms,
    const float* __restrict__ cHalf, float* __restrict__ qout,
    float* __restrict__ iout, float* __restrict__ lout, int useT)
{
    __shared__ float  As[2][32 * 68];
    __shared__ float4 Bs[2][512];
    const int tid  = threadIdx.x;
    const int row0 = blockIdx.x * 64;
    const int ty = tid >> 4, tx = tid & 15;
    const int ar = tid >> 2, ak = (tid & 3) * 4;
    const int bk = tid >> 4, bj = tid & 15;
    float bestv[4]; int bestj[4];
#pragma unroll
    for (int i = 0; i < 4; ++i) { bestv[i] = -3.4e38f; bestj[i] = 0; }
    float acc[4][4];
    float4 pa0, pa1, pb0, pb1;
    {
        const float* xp = x + (size_t)(row0 + ar) * DIM + ak;
        pa0 = *(const float4*)xp;
        pa1 = *(const float4*)(xp + 16);
        const float* ep = e + (size_t)bk * NC + bj * 4;
        pb0 = *(const float4*)ep;
        pb1 = *(const float4*)(ep + 16 * NC);
    }
    int buf = 0;
    for (int c = 0; c < 1024; ++c) {
        const int kc = c & 7;
#pragma unroll
        for (int q = 0; q < 4; ++q) As[buf][(ak + q) * 68 + ar]      = ((const float*)&pa0)[q];
#pragma unroll
        for (int q = 0; q < 4; ++q) As[buf][(16 + ak + q) * 68 + ar] = ((const float*)&pa1)[q];
        Bs[buf][bk * 16 + bj]        = pb0;
        Bs[buf][(bk + 16) * 16 + bj] = pb1;
        __syncthreads();
        if (c + 1 < 1024) {
            int j0n  = ((c + 1) >> 3) * 64;
            int kk0n = ((c + 1) & 7) * 32;
            const float* xp = x + (size_t)(row0 + ar) * DIM + kk0n + ak;
            pa0 = *(const float4*)xp;
            pa1 = *(const float4*)(xp + 16);
            const float* ep = e + (size_t)(kk0n + bk) * NC + j0n + bj * 4;
            pb0 = *(const float4*)ep;
            pb1 = *(const float4*)(ep + 16 * NC);
        }
        if (kc == 0) {
#pragma unroll
            for (int i = 0; i < 4; ++i)
#pragma unroll
                for (int j = 0; j < 4; ++j) acc[i][j] = 0.f;
        }
#pragma unroll
        for (int k = 0; k < 32; ++k) {
            float4 a = *(const float4*)&As[buf][k * 68 + ty * 4];
            float4 b = *(const float4*)&Bs[buf][k * 16 + tx];
            acc[0][0] += a.x * b.x; acc[0][1] += a.x * b.y; acc[0][2] += a.x * b.z; acc[0][3] += a.x * b.w;
            acc[1][0] += a.y * b.x; acc[1][1] += a.y * b.y; acc[1][2] += a.y * b.z; acc[1][3] += a.y * b.w;
            acc[2][0] += a.z * b.x; acc[2][1] += a.z * b.y; acc[2][2] += a.z * b.z; acc[2][3] += a.z * b.w;
            acc[3][0] += a.w * b.x; acc[3][1] += a.w * b.y; acc[3][2] += a.w * b.z; acc[3][3] += a.w * b.w;
        }
        if (kc == 7) {
            int j0 = (c >> 3) * 64;
            float4 ch = *(const float4*)&cHalf[j0 + tx * 4];
            int jb0 = j0 + tx * 4;
#pragma unroll
            for (int i = 0; i < 4; ++i)
#pragma unroll
                for (int j = 0; j < 4; ++j) {
                    float s = acc[i][j] - ((const float*)&ch)[j];
                    if (s > bestv[i]) { bestv[i] = s; bestj[i] = jb0 + j; }
                }
        }
        buf ^= 1;
    }
    __syncthreads();
    float* redv   = &As[0][0];
    int*   redj   = (int*)&As[0][1024];
    int*   idxbuf = (int*)&As[1][0];
#pragma unroll
    for (int i = 0; i < 4; ++i) {
        int r = ty * 4 + i;
        redv[r * 16 + tx] = bestv[i];
        redj[r * 16 + tx] = bestj[i];
    }
    __syncthreads();
    if (tid < 64) {
        float bvv = redv[tid * 16];
        int   bj2 = redj[tid * 16];
#pragma unroll
        for (int t = 1; t < 16; ++t) {
            float v = redv[tid * 16 + t];
            int   j = redj[tid * 16 + t];
            if (v > bvv || (v == bvv && j < bj2)) { bvv = v; bj2 = j; }
        }
        iout[row0 + tid] = (float)bj2;
        idxbuf[tid] = bj2;
        float rl = norms[row0 + tid] - 2.0f * bvv;
#pragma unroll
        for (int off = 32; off; off >>= 1) rl += __shfl_down(rl, off, 64);
        if (tid == 0) atomicAdd(lout, rl * LOSS_SCALE);
    }
    __syncthreads();
    {
        const int rr = tid >> 6, lane = tid & 63;
        for (int r = rr; r < 64; r += 4) {
            int j = idxbuf[r];
            float4 v;
            if (useT) {
                v = *(const float4*)&eT[(size_t)j * DIM + lane * 4];
            } else {
                int d = lane * 4;
                v.x = e[(size_t)d * NC + j];
                v.y = e[(size_t)(d + 1) * NC + j];
                v.z = e[(size_t)(d + 2) * NC + j];
                v.w = e[(size_t)(d + 3) * NC + j];
            }
            *(float4*)&qout[(size_t)(row0 + r) * DIM + lane * 4] = v;
        }
    }
}

// ======================= launch =======================

extern "C" void kernel_launch(void* const* d_in, const int* in_sizes, int n_in,
                              void* d_out, int out_size, void* d_ws, size_t ws_size,
                              hipStream_t stream) {
    const float* x = (const float*)d_in[0];   // [32768, 256]
    const float* e = (const float*)d_in[1];   // [256, 8192]

    float* qout = (float*)d_out;
    float* iout = qout + (size_t)NROW * DIM;
    float* lout = iout + NROW;

    char* ws = (char*)d_ws;
    const size_t offAh    = 0;                    // 32768*576*2 = 37,748,736
    const size_t offBh    = offAh + 37748736;     //  8192*576*2 =  9,437,184
    const size_t offNorms = offBh + 9437184;      //    131,072
    const size_t offCH    = offNorms + 131072;    //     32,768
    const size_t offPV    = offCH + 32768;        //    524,288
    const size_t offPJ    = offPV + 524288;       //    524,288
    const size_t offPSV   = offPJ + 524288;       //    524,288
    const size_t offPV2   = offPSV + 524288;      //  2,097,152
    const size_t offPJ2   = offPV2 + 2097152;     //  2,097,152
    const size_t offList  = offPJ2 + 2097152;     //     65,536
    const size_t offCnt   = offList + 65536;      //        256
    const size_t needFast = offCnt + 256;         // ~53.2 MB (proven: >=55.7 MB available)

    hipMemsetAsync(lout, 0, sizeof(float), stream);

    if (ws_size >= needFast) {
        unsigned short* Ah = (unsigned short*)(ws + offAh);
        unsigned short* Bh = (unsigned short*)(ws + offBh);
        float* norms = (float*)(ws + offNorms);
        float* cHalf = (float*)(ws + offCH);
        float* pv    = (float*)(ws + offPV);
        int*   pj    = (int*)(ws + offPJ);
        float* psv   = (float*)(ws + offPSV);
        float* pv2   = (float*)(ws + offPV2);
        int*   pj2   = (int*)(ws + offPJ2);
        int*   list  = (int*)(ws + offList);
        int*   cnt   = (int*)(ws + offCnt);

        hipMemsetAsync(cnt, 0, sizeof(int), stream);
        prep_a_k<<<NROW / 4, 256, 0, stream>>>(x, Ah, norms);
        code_norms_k<<<NC / 256, 256, 0, stream>>>(e, Bh, cHalf);
        prep_b_k<<<dim3(NC / 32, DIM / 32), dim3(32, 8), 0, stream>>>(e, Bh);
        // cheap pass (R18): barrier-free main loop, per-wave private B rings
        vq_cheap_k<<<1024, 512, 0, stream>>>(Ah, Bh, cHalf, pv, pj, psv);
        // merge + flag + finalize non-flagged
        vq_reduce_k<<<NROW / 64, 256, 0, stream>>>(
            pv, pj, psv, norms, Bh, qout, iout, lout, list, cnt);
        // precise pass (K=768, exact fp32 cHalf) on flagged rows: 32 col-splits of 256
        vq_gemm_k<24, 2, 5, true><<<(CAP / 128) * 32, 256, 0, stream>>>(
            Ah, Bh, cHalf, pv2, pj2, nullptr, list, cnt);
        vq_reduce2_k<<<CAP / 64, 256, 0, stream>>>(
            pv2, pj2, list, cnt, norms, Bh, qout, iout, lout);
    } else {
        // round-1 fp32 fallback
        float* fws   = (float*)d_ws;
        float* norms = fws;
        float* cHalf = fws + NROW;
        float* eT    = fws + NROW + NC;
        size_t need_T = (size_t)(NROW + NC) * sizeof(float) + (size_t)NC * DIM * sizeof(float);
        int useT = (ws_size >= need_T) ? 1 : 0;
        row_norms_k<<<NROW / 4, 256, 0, stream>>>(x, norms);
        code_norms_fb_k<<<NC / 256, 256, 0, stream>>>(e, cHalf);
        if (useT)
            transpose_k<<<dim3(NC / 32, DIM / 32), dim3(32, 8), 0, stream>>>(e, eT);
        vq_main_k<<<NROW / 64, 256, 0, stream>>>(x, e, eT, norms, cHalf, qout, iout, lout, useT);
    }
}

// Round 12
// 343.690 us; speedup vs baseline: 1.0858x; 1.0858x over previous
//
#include <hip/hip_runtime.h>
#include <hip/hip_fp16.h>

#define NROW 32768
#define DIM  256
#define NC   8192
#define CAP  16384                     // max rescued rows (expect ~2500)
#define MARGINF 0.25f                  // flag threshold: not-flagged => true cheap gap >= 0.125
#define BIAS 512.0f                    // cheap-score bias: guarantees all cheap scores negative
#define AST 576                        // A' row: [hi 256 | ones 32 | lo 256 | pad 32] halves
#define BST 576                        // B' row: [hi 256 | ch 32   | lo 256 | pad 32] halves
#define LOSS_SCALE (1.0f / 8388608.0f)

typedef __attribute__((ext_vector_type(8))) _Float16 half8;
typedef __attribute__((ext_vector_type(4))) _Float16 half4;
typedef __attribute__((ext_vector_type(4))) float   floatx4;
typedef const __attribute__((address_space(1))) void* gas_p;
typedef __attribute__((address_space(3))) void*       las_p;

static __device__ __forceinline__ unsigned short f2hb(float f) {
    _Float16 h = (_Float16)f;
    unsigned short u;
    __builtin_memcpy(&u, &h, 2);
    return u;
}
static __device__ __forceinline__ unsigned umin_(unsigned a, unsigned b) { return a < b ? a : b; }
static __device__ __forceinline__ unsigned umax_(unsigned a, unsigned b) { return a > b ? a : b; }

// ======================= prep kernels (fast path) =======================

__global__ void prep_a_k(const float* __restrict__ x, unsigned short* __restrict__ Ah,
                         float* __restrict__ norms) {
    int row  = blockIdx.x * 4 + (threadIdx.x >> 6);
    int lane = threadIdx.x & 63;
    const float4 v = ((const float4*)(x + (size_t)row * DIM))[lane];
    float s = v.x * v.x + v.y * v.y + v.z * v.z + v.w * v.w;
#pragma unroll
    for (int off = 32; off; off >>= 1) s += __shfl_down(s, off, 64);
    if (lane == 0) norms[row] = s;
    ushort4 hi4 = make_ushort4(f2hb(v.x), f2hb(v.y), f2hb(v.z), f2hb(v.w));
    ushort4 lo4 = make_ushort4(f2hb(v.x - (float)(_Float16)v.x),
                               f2hb(v.y - (float)(_Float16)v.y),
                               f2hb(v.z - (float)(_Float16)v.z),
                               f2hb(v.w - (float)(_Float16)v.w));
    unsigned short* rp = Ah + (size_t)row * AST;
    *(ushort4*)(rp + lane * 4)       = hi4;
    *(ushort4*)(rp + 288 + lane * 4) = lo4;
    if (lane < 8) {                    // legacy ones block (unused by cheap)
        ushort4 ob = make_ushort4(0, 0, 0, 0);
        if (lane == 0) { ob.x = 0x3C00; ob.y = 0x3C00; }
        *(ushort4*)(rp + 256 + lane * 4) = ob;
    }
}

__global__ void code_norms_k(const float* __restrict__ e, unsigned short* __restrict__ Bh,
                             float* __restrict__ cHalf) {
    int j = blockIdx.x * 256 + threadIdx.x;
    float s = 0.f;
    for (int d = 0; d < DIM; ++d) { float v = e[(size_t)d * NC + j]; s += v * v; }
    cHalf[j] = 0.5f * s;
    float t = -0.5f * s - BIAS;        // legacy ch block (unused by cheap)
    unsigned short hi = f2hb(t);
    _Float16 hf; __builtin_memcpy(&hf, &hi, 2);
    unsigned short lo = f2hb(t - (float)hf);
    unsigned short* p = Bh + (size_t)j * BST + 256;
    p[0] = hi; p[1] = lo;
    for (int k2 = 2; k2 < 32; ++k2) p[k2] = 0;
}

__global__ void prep_b_k(const float* __restrict__ e, unsigned short* __restrict__ Bh) {
    __shared__ float t[32][33];
    int jb = blockIdx.x * 32, db = blockIdx.y * 32;
#pragma unroll
    for (int i = 0; i < 4; ++i)
        t[threadIdx.y + i * 8][threadIdx.x] =
            e[(size_t)(db + threadIdx.y + i * 8) * NC + jb + threadIdx.x];
    __syncthreads();
#pragma unroll
    for (int i = 0; i < 4; ++i) {
        int j = jb + threadIdx.y + i * 8;
        int d = db + threadIdx.x;
        float val = t[threadIdx.x][threadIdx.y + i * 8];
        Bh[(size_t)j * BST + d]       = f2hb(val);
        Bh[(size_t)j * BST + 288 + d] = f2hb(val - (float)(_Float16)val);
    }
}

// ======================= R15 cheap kernel (best: 174 us) — reverted verbatim =======================
// R16/R17/R18 post-mortems: stagger (reg-cost and zero-cost) and barrier-free private rings
// all regressed vs R15. At 2 waves/SIMD there is no TLP to decouple the LDS and MFMA
// phases regardless of sync structure; higher occupancy is blocked by the register budget
// (acc 64 AGPR + frags), and halving the wave tile raises LDS reads/FLOP. R15 is the
// plateau for this tile shape: counted vmcnt(2) + counted lgkmcnt(4) + half-A-resident +
// MFMA-first bodies.

#define WAITBAR asm volatile("s_waitcnt vmcnt(2) lgkmcnt(4)\n\ts_barrier" ::: "memory")

__global__ __launch_bounds__(512, 2) void vq_cheap_k(
    const unsigned short* __restrict__ Ah, const unsigned short* __restrict__ Bh,
    const float* __restrict__ cHalf,
    float* __restrict__ pv, int* __restrict__ pj, float* __restrict__ psv)
{
    __shared__ __align__(16) _Float16 Asl[8][4096];   // 64 KB: A staging (chunks 4-7 read all loop)
    __shared__ __align__(16) _Float16 Bsl[4][8192];   // 64 KB: 4-deep chunk ring
    __shared__ float chl[2048];                       //  8 KB

    const int tid  = threadIdx.x;
    const int js   = blockIdx.x & 3;
    const int rb   = blockIdx.x >> 2;
    const int row0 = rb * 128, col0 = js * 2048;
    const int lane = tid & 63, l15 = lane & 15, lq = lane >> 4;
    const int wave = tid >> 6;                 // 0..7
    const int wr = (wave >> 2) * 64;           // 0 / 64
    const int wc = (wave & 3) * 64;            // 0 / 64 / 128 / 192
    const int sr = tid >> 2;                   // staging row 0..127
    const int ks = (((tid & 3) ^ (sr & 3) ^ ((sr >> 2) & 3))) * 8;  // swizzled global k-offset

    // ---- chl first: its compiler-inserted vmcnt wait covers only 1 load ----
    {
        float4 a = ((const float4*)(cHalf + col0))[tid];
        a.x += BIAS; a.y += BIAS; a.z += BIAS; a.w += BIAS;
        ((float4*)chl)[tid] = a;
    }

    // ---- A-hi -> LDS (one inst per chunk) ----
    const unsigned short* Abase = Ah + (size_t)(row0 + sr) * AST + ks;
#pragma unroll
    for (int c = 0; c < 8; ++c)
        __builtin_amdgcn_global_load_lds((gas_p)(Abase + c * 32), (las_p)&Asl[c][tid * 8], 16, 0, 0);

#define LOADB(JT_, C_, BUF_)                                                                  \
    do {                                                                                      \
        const unsigned short* bb_ = Bh + (size_t)(col0 + (JT_) * 256 + sr) * BST + (C_) * 32 + ks; \
        _Float16* lb_ = &Bsl[(BUF_)][tid * 8];                                                \
        __builtin_amdgcn_global_load_lds((gas_p)bb_,               (las_p)lb_,          16, 0, 0); \
        __builtin_amdgcn_global_load_lds((gas_p)(bb_ + 128 * BST), (las_p)(lb_ + 4096), 16, 0, 0); \
    } while (0)

    // ---- prime the ring: chunks 0,1,2 in flight ----
    LOADB(0, 0, 0);
    LOADB(0, 1, 1);
    LOADB(0, 2, 2);

    unsigned k1[16], k2[16];
#pragma unroll
    for (int s = 0; s < 16; ++s) { k1[s] = 0xFFFFFFFFu; k2[s] = 0xFFFFFFFFu; }

    const floatx4 fzero = {0.0f, 0.0f, 0.0f, 0.0f};
    floatx4 acc[4][4];
#pragma unroll
    for (int rf = 0; rf < 4; ++rf)
#pragma unroll
        for (int cf = 0; cf < 4; ++cf) acc[rf][cf] = fzero;

    // outstanding: 8 A + 6 B (chl already retired). vmcnt(2) -> A all staged,
    // B chunks 0,1 staged, chunk 2 in flight.
    WAITBAR;

    // ---- one-time: A chunks 0-3 -> registers (64 VGPR) ----
    half8 ar[4][4];
#pragma unroll
    for (int c = 0; c < 4; ++c)
#pragma unroll
        for (int rf = 0; rf < 4; ++rf) {
            const int m = wr + rf * 16 + l15;
            const int g = lq ^ (m & 3) ^ ((m >> 2) & 3);
            ar[c][rf] = *(const half8*)&Asl[c][m * 32 + g * 8];
        }

    // ---- prime bf with chunk 0; af first used body 4, first written at end of body 3 ----
    half8 af[4], bf[4];
#pragma unroll
    for (int cf = 0; cf < 4; ++cf) {
        const int n = wc + cf * 16 + l15;
        const int g = lq ^ (n & 3) ^ ((n >> 2) & 3);
        bf[cf] = *(const half8*)&Bsl[0][n * 32 + g * 8];
    }

    for (int jt = 0; jt < 8; ++jt) {
#pragma unroll
        for (int c = 0; c < 8; ++c) {
            // prefetch chunk t+3 into buf (t+3)&3 (slot's reads were consumed by
            // body t-1's MFMA -> drained at least one barrier before this write)
            if (c <= 4) LOADB(jt, c + 3, (c + 3) & 3);
            else        LOADB((jt + 1) & 7, c - 5, (c + 3) & 3);

            // MFMA chunk t FIRST: A from ar (c<4) or af (read end of body t-1);
            // B from bf (read end of body t-1). Compiler inserts the precise
            // lgkmcnt before each consuming MFMA (bf reads may cross the barrier).
            __builtin_amdgcn_s_setprio(1);
            if (c < 4) {
#pragma unroll
                for (int rf = 0; rf < 4; ++rf)
#pragma unroll
                    for (int cf = 0; cf < 4; ++cf)
                        acc[rf][cf] = __builtin_amdgcn_mfma_f32_16x16x32_f16(
                            ar[c][rf], bf[cf], acc[rf][cf], 0, 0, 0);
            } else {
#pragma unroll
                for (int rf = 0; rf < 4; ++rf)
#pragma unroll
                    for (int cf = 0; cf < 4; ++cf)
                        acc[rf][cf] = __builtin_amdgcn_mfma_f32_16x16x32_f16(
                            af[rf], bf[cf], acc[rf][cf], 0, 0, 0);
            }
            __builtin_amdgcn_s_setprio(0);
            __builtin_amdgcn_sched_barrier(0);  // keep everything below the MFMAs

            if (c == 7) {
                // ---- per-jt epilogue BEFORE the reads: chl reads are consumed
                // in-place; issuing them after bf would force an in-order drain
                // of bf at the barrier. ----
#pragma unroll
                for (int cf = 0; cf < 4; ++cf) {
                    const unsigned colb = (unsigned)(jt * 256 + wc + cf * 16 + l15); // 11-bit local col
                    const float ch = chl[colb];
#pragma unroll
                    for (int rf = 0; rf < 4; ++rf)
#pragma unroll
                        for (int r = 0; r < 4; ++r) {
                            float s = acc[rf][cf][r] - ch;
                            unsigned key = (__float_as_uint(s) & 0xFFFFF800u) | colb;
                            int slot = rf * 4 + r;
                            unsigned t = umax_(key, k1[slot]);
                            k1[slot] = umin_(k1[slot], key);
                            k2[slot] = umin_(k2[slot], t);
                        }
                }
#pragma unroll
                for (int rf = 0; rf < 4; ++rf)
#pragma unroll
                    for (int cf = 0; cf < 4; ++cf) acc[rf][cf] = fzero;
            }

            // ds_reads for chunk t+1 (staged + published by WAITBAR(t-1)); these
            // may remain in flight across the barrier (lgkmcnt(4)).
            if (((c + 1) & 7) >= 4) {
#pragma unroll
                for (int rf = 0; rf < 4; ++rf) {
                    const int m = wr + rf * 16 + l15;
                    const int g = lq ^ (m & 3) ^ ((m >> 2) & 3);
                    af[rf] = *(const half8*)&Asl[(c + 1) & 7][m * 32 + g * 8];
                }
            }
#pragma unroll
            for (int cf = 0; cf < 4; ++cf) {
                const int n = wc + cf * 16 + l15;
                const int g = lq ^ (n & 3) ^ ((n >> 2) & 3);
                bf[cf] = *(const half8*)&Bsl[(c + 1) & 3][n * 32 + g * 8];
            }

            // end of body t: retire chunk t+2 (t+3 in flight); allow this body's
            // newest <=4 LDS reads to cross the barrier.
            WAITBAR;
        }
    }
#undef LOADB

    // ---- cross-lane merge over the 16 l15-lanes of each row-group ----
#pragma unroll
    for (int st = 1; st < 16; st <<= 1) {
#pragma unroll
        for (int s = 0; s < 16; ++s) {
            unsigned o1 = (unsigned)__shfl_xor((int)k1[s], st, 64);
            unsigned o2 = (unsigned)__shfl_xor((int)k2[s], st, 64);
            unsigned t = umax_(k1[s], o1);
            k1[s] = umin_(k1[s], o1);
            k2[s] = umin_(umin_(k2[s], o2), t);
        }
    }

    // ---- merge the four column-group waves per row through LDS ----
    __syncthreads();                            // full drain: dummy tail loads + stray reads
    unsigned* mk1 = (unsigned*)&Asl[0][0];      // [128 rows][4 col-groups]
    unsigned* mk2 = (unsigned*)&Asl[1][0];
    if (l15 == 0) {
#pragma unroll
        for (int rf = 0; rf < 4; ++rf)
#pragma unroll
            for (int r = 0; r < 4; ++r) {
                int rloc = wr + rf * 16 + lq * 4 + r;
                int slot = rf * 4 + r;
                mk1[rloc * 4 + (wave & 3)] = k1[slot];
                mk2[rloc * 4 + (wave & 3)] = k2[slot];
            }
    }
    __syncthreads();
    if (tid < 128) {
        unsigned a0 = mk1[tid * 4], a1 = mk1[tid * 4 + 1], a2 = mk1[tid * 4 + 2], a3 = mk1[tid * 4 + 3];
        unsigned x = umin_(a0, a1), y = umax_(a0, a1);
        unsigned z = umin_(a2, a3), w = umax_(a2, a3);
        unsigned m1  = umin_(x, z);
        unsigned sm1 = umin_(umax_(x, z), umin_(y, w));            // 2nd-best of the four bests
        unsigned s0 = mk2[tid * 4], s1 = mk2[tid * 4 + 1], s2 = mk2[tid * 4 + 2], s3 = mk2[tid * 4 + 3];
        unsigned m2 = umin_(umin_(umin_(s0, s1), umin_(s2, s3)), sm1);
        pv[(size_t)js * NROW + row0 + tid]  = __uint_as_float(m1 & 0xFFFFF800u);
        pj[(size_t)js * NROW + row0 + tid]  = (int)(m1 & 2047u) + js * 2048;
        psv[(size_t)js * NROW + row0 + tid] = __uint_as_float(m2 & 0xFFFFF800u);
    }
}

#undef WAITBAR

// ======================= rescue GEMM: R19 — 3-deep ring + counted vmcnt =======================
// The rescue pass still used the R8 full-drain __syncthreads structure (the exact
// inefficiency counted waits fixed in the cheap pass, R11: +6%). R19: 3-buffer ring
// (As/Bs[3], 48 KB total -> also LDS-allows 3 blocks/CU vs 2) with prefetch depth 2 and
// "s_waitcnt vmcnt(4) lgkmcnt(0); s_barrier" at body top.
// Ledger (T = jt*CHUNKS+c; CHUNKS=24, 24%3==0 -> slot = c%3 compile-time across jt):
//   prologue: LOAD4(0,0)->slot0, LOAD4(0,1)->slot1            [8 loads in flight]
//   body (jt,c): WAIT vmcnt(4) [retires chunk T: issued 2 bodies ago - stall-free]
//                + lgkmcnt(0) [prev body's frag reads drained - free, MFMA consumed them]
//                + barrier; LOAD4(T+2) into slot (c+2)%3 = chunk T-1's slot (reads
//                drained >=1 barrier ago); frag reads(T) from slot c%3; MFMA; epilogue
//                at c==CHUNKS-1. Tail loads skipped (counted waits pass vacuously).
//   Early-return blocks (row0>=nact) exit before the first barrier (uniform per block).

template<bool RESCUE>
static __device__ __forceinline__ void chunk_off(int c, int& ac, int& bc) {
    if constexpr (RESCUE) {
        if (c < 8)       { ac = c * 32;              bc = c * 32; }
        else if (c < 16) { ac = (c - 8) * 32;        bc = 288 + (c - 8) * 32; }
        else             { ac = 288 + (c - 16) * 32; bc = (c - 16) * 32; }
    } else {
        ac = c * 32; bc = c * 32;
    }
}

#define GWAIT asm volatile("s_waitcnt vmcnt(4) lgkmcnt(0)\n\ts_barrier" ::: "memory")

template<int CHUNKS, int JT, int JSB, bool RESCUE>
__global__ __launch_bounds__(256, 2) void vq_gemm_k(
    const unsigned short* __restrict__ Ah, const unsigned short* __restrict__ Bh,
    const float* __restrict__ cHalf,
    float* __restrict__ pv, int* __restrict__ pj, float* __restrict__ psv,
    const int* __restrict__ list, const int* __restrict__ cnt)
{
    static_assert(CHUNKS % 3 == 0, "3-deep ring requires CHUNKS % 3 == 0");
    __shared__ __align__(16) _Float16 As[3][4096];    // 24 KB
    __shared__ __align__(16) _Float16 Bs[3][4096];    // 24 KB

    const int tid  = threadIdx.x;
    const int js   = blockIdx.x & ((1 << JSB) - 1);
    const int rb   = blockIdx.x >> JSB;
    const int row0 = rb * 128, col0 = js * (JT * 128);
    const int lane = tid & 63, l15 = lane & 15, lq = lane >> 4;
    const int wave = tid >> 6;
    const int wrow = (wave >> 1) * 64, wcol = (wave & 1) * 64;
    const int sr = tid >> 2, sp = (tid & 3) * 8;

    int nact = 0;
    if constexpr (RESCUE) {
        nact = *cnt;
        if (row0 >= nact) return;
    }

    const unsigned short *Abase0, *Abase1;
    if constexpr (RESCUE) {
        int i0 = row0 + sr, i1 = i0 + 64;
        int r0 = (i0 < nact) ? list[i0] : 0;
        int r1 = (i1 < nact) ? list[i1] : 0;
        Abase0 = Ah + (size_t)r0 * AST + sp;
        Abase1 = Ah + (size_t)r1 * AST + sp;
    } else {
        Abase0 = Ah + (size_t)(row0 + sr) * AST + sp;
        Abase1 = Abase0 + 64 * AST;
    }

    unsigned k1[16], k2[16];
    float bvf[16]; int bjf[16];
#pragma unroll
    for (int s = 0; s < 16; ++s) {
        k1[s] = 0xFFFFFFFFu; k2[s] = 0xFFFFFFFFu;
        bvf[s] = -3.4e38f; bjf[s] = 0;
    }

    const floatx4 fzero = {0.0f, 0.0f, 0.0f, 0.0f};
    floatx4 acc[4][4];
#pragma unroll
    for (int rf = 0; rf < 4; ++rf)
#pragma unroll
        for (int cf = 0; cf < 4; ++cf) acc[rf][cf] = fzero;

    const unsigned short* Bb0 = Bh + (size_t)(col0 + sr) * BST + sp;

    // LOAD4T(jt_, c_): stage chunk (jt_, c_) into ring slot c_%3.
#define LOAD4T(JT_, C_)                                                                      \
    do {                                                                                     \
        int an_, bn_;                                                                        \
        chunk_off<RESCUE>((C_), an_, bn_);                                                   \
        const unsigned short* bb_ = Bb0 + (size_t)(JT_) * (128 * BST);                       \
        _Float16* la_ = &As[(C_) % 3][tid * 8];                                              \
        _Float16* lb_ = &Bs[(C_) % 3][tid * 8];                                              \
        __builtin_amdgcn_global_load_lds((gas_p)(Abase0 + an_),            (las_p)la_,          16, 0, 0); \
        __builtin_amdgcn_global_load_lds((gas_p)(Abase1 + an_),            (las_p)(la_ + 2048), 16, 0, 0); \
        __builtin_amdgcn_global_load_lds((gas_p)(bb_ + bn_),               (las_p)lb_,          16, 0, 0); \
        __builtin_amdgcn_global_load_lds((gas_p)(bb_ + 64 * BST + bn_),    (las_p)(lb_ + 2048), 16, 0, 0); \
    } while (0)

    // prime: chunks (0,0) and (0,1) in flight
    LOAD4T(0, 0);
    LOAD4T(0, 1);

    for (int jt = 0; jt < JT; ++jt) {
#pragma unroll
        for (int c = 0; c < CHUNKS; ++c) {
            // retire chunk (jt,c) [issued 2 bodies ago]; keep next chunk in flight;
            // prev body's frag reads drained (consumed by its MFMAs) -> slot reuse safe.
            GWAIT;
            if (c + 2 < CHUNKS)       LOAD4T(jt, c + 2);
            else if (jt + 1 < JT)     LOAD4T(jt + 1, c + 2 - CHUNKS);
            // (note: (c+2-CHUNKS)%3 == (c+2)%3 since CHUNKS%3==0 -> slot consistent)

            half8 af[4], bf[4];
#pragma unroll
            for (int rf = 0; rf < 4; ++rf)
                af[rf] = *(const half8*)&As[c % 3][(wrow + rf * 16 + l15) * 32 + lq * 8];
#pragma unroll
            for (int cf = 0; cf < 4; ++cf)
                bf[cf] = *(const half8*)&Bs[c % 3][(wcol + cf * 16 + l15) * 32 + lq * 8];
#pragma unroll
            for (int rf = 0; rf < 4; ++rf)
#pragma unroll
                for (int cf = 0; cf < 4; ++cf)
                    acc[rf][cf] = __builtin_amdgcn_mfma_f32_16x16x32_f16(
                        af[rf], bf[cf], acc[rf][cf], 0, 0, 0);

            if (c == CHUNKS - 1) {
                if constexpr (RESCUE) {
                    const int colbase = col0 + jt * 128 + wcol;
#pragma unroll
                    for (int cf = 0; cf < 4; ++cf) {
                        const int col = colbase + cf * 16 + l15;
                        const float ch = cHalf[col];
#pragma unroll
                        for (int rf = 0; rf < 4; ++rf)
#pragma unroll
                            for (int r = 0; r < 4; ++r) {
                                float s = acc[rf][cf][r] - ch;
                                int slot = rf * 4 + r;
                                if (s > bvf[slot]) { bvf[slot] = s; bjf[slot] = col; }
                            }
                    }
                } else {
                    const unsigned colloc = (unsigned)(jt * 128 + wcol);
#pragma unroll
                    for (int cf = 0; cf < 4; ++cf) {
                        const unsigned colb = colloc + cf * 16 + l15;
#pragma unroll
                        for (int rf = 0; rf < 4; ++rf)
#pragma unroll
                            for (int r = 0; r < 4; ++r) {
                                unsigned key = (__float_as_uint(acc[rf][cf][r]) & 0xFFFFF800u) | colb;
                                int slot = rf * 4 + r;
                                unsigned t = umax_(key, k1[slot]);
                                k1[slot] = umin_(k1[slot], key);
                                k2[slot] = umin_(k2[slot], t);
                            }
                    }
                }
#pragma unroll
                for (int rf = 0; rf < 4; ++rf)
#pragma unroll
                    for (int cf = 0; cf < 4; ++cf) acc[rf][cf] = fzero;
            }
        }
    }
#undef LOAD4T

#pragma unroll
    for (int st = 1; st < 16; st <<= 1) {
#pragma unroll
        for (int s = 0; s < 16; ++s) {
            if constexpr (RESCUE) {
                float v2 = __shfl_xor(bvf[s], st, 64);
                int   j2 = __shfl_xor(bjf[s], st, 64);
                if (v2 > bvf[s] || (v2 == bvf[s] && j2 < bjf[s])) { bvf[s] = v2; bjf[s] = j2; }
            } else {
                unsigned o1 = (unsigned)__shfl_xor((int)k1[s], st, 64);
                unsigned o2 = (unsigned)__shfl_xor((int)k2[s], st, 64);
                unsigned t = umax_(k1[s], o1);
                k1[s] = umin_(k1[s], o1);
                k2[s] = umin_(umin_(k2[s], o2), t);
            }
        }
    }

    __syncthreads();
    if constexpr (RESCUE) {
        float* mv = (float*)&As[0][0];
        int*   mj = (int*)&Bs[0][0];
        if (l15 == 0) {
#pragma unroll
            for (int rf = 0; rf < 4; ++rf)
#pragma unroll
                for (int r = 0; r < 4; ++r) {
                    int rloc = wrow + rf * 16 + lq * 4 + r;
                    int slot = rf * 4 + r;
                    mv[rloc * 2 + (wave & 1)] = bvf[slot];
                    mj[rloc * 2 + (wave & 1)] = bjf[slot];
                }
        }
        __syncthreads();
        if (tid < 128) {
            float v0 = mv[tid * 2], v1 = mv[tid * 2 + 1];
            int   j0 = mj[tid * 2], j1 = mj[tid * 2 + 1];
            bool take1 = (v1 > v0) || (v1 == v0 && j1 < j0);
            pv[(size_t)js * CAP + row0 + tid] = take1 ? v1 : v0;
            pj[(size_t)js * CAP + row0 + tid] = take1 ? j1 : j0;
        }
    } else {
        unsigned* mk1 = (unsigned*)&As[0][0];
        unsigned* mk2 = (unsigned*)&Bs[0][0];
        if (l15 == 0) {
#pragma unroll
            for (int rf = 0; rf < 4; ++rf)
#pragma unroll
                for (int r = 0; r < 4; ++r) {
                    int rloc = wrow + rf * 16 + lq * 4 + r;
                    int slot = rf * 4 + r;
                    mk1[rloc * 2 + (wave & 1)] = k1[slot];
                    mk2[rloc * 2 + (wave & 1)] = k2[slot];
                }
        }
        __syncthreads();
        if (tid < 128) {
            unsigned a1 = mk1[tid * 2], b1 = mk1[tid * 2 + 1];
            unsigned a2 = mk2[tid * 2], b2 = mk2[tid * 2 + 1];
            unsigned m1 = umin_(a1, b1);
            unsigned m2 = umin_(umin_(a2, b2), umax_(a1, b1));
            pv[(size_t)js * NROW + row0 + tid] = __uint_as_float(m1 & 0xFFFFF800u);
            pj[(size_t)js * NROW + row0 + tid] = (int)(m1 & 2047u) + js * (JT * 128);
            psv[(size_t)js * NROW + row0 + tid] = __uint_as_float(m2 & 0xFFFFF800u);
        }
    }
}

// ======================= cheap reduce: merge splits, flag, gather =======================

__global__ void vq_reduce_k(const float* __restrict__ pv, const int* __restrict__ pj,
                            const float* __restrict__ psv,
                            const float* __restrict__ norms, const unsigned short* __restrict__ Bh,
                            float* __restrict__ qout, float* __restrict__ iout,
                            float* __restrict__ lout, int* __restrict__ list,
                            int* __restrict__ cnt)
{
    __shared__ int jbuf[64];
    const int row0 = blockIdx.x * 64;
    const int tid = threadIdx.x;
    if (tid < 64) {
        int row = row0 + tid;
        float bv = pv[row]; int bj = pj[row]; float sv = psv[row];
#pragma unroll
        for (int s = 1; s < 4; ++s) {
            float v = pv[(size_t)s * NROW + row];
            int   j = pj[(size_t)s * NROW + row];
            float s2 = psv[(size_t)s * NROW + row];
            bool better = (v > bv) || (v == bv && j < bj);
            float loseBest = better ? bv : v;
            sv = fmaxf(fmaxf(sv, s2), loseBest);
            if (better) { bv = v; bj = j; }
        }
        bool flagged = (bv - sv) < MARGINF;
        if (flagged) {
            int idx = atomicAdd(cnt, 1);
            if (idx < CAP) {
                list[idx] = row;
                jbuf[tid] = -1;
            } else {
                flagged = false;
            }
        }
        float rl = 0.f;
        if (!flagged) {
            iout[row] = (float)bj;
            jbuf[tid] = bj;
            rl = norms[row] - 2.0f * (bv + BIAS - 0.0625f);
        }
#pragma unroll
        for (int off = 32; off; off >>= 1) rl += __shfl_down(rl, off, 64);
        if (tid == 0) atomicAdd(lout, rl * LOSS_SCALE);
    }
    __syncthreads();
    const int lane = tid & 63;
    for (int r = tid >> 6; r < 64; r += 4) {
        int j = jbuf[r];
        if (j >= 0) {
            const _Float16* bp = (const _Float16*)Bh + (size_t)j * BST + lane * 4;
            half4 h = *(const half4*)bp;
            half4 l = *(const half4*)(bp + 288);
            float4 v;
            v.x = (float)h[0] + (float)l[0];
            v.y = (float)h[1] + (float)l[1];
            v.z = (float)h[2] + (float)l[2];
            v.w = (float)h[3] + (float)l[3];
            *(float4*)&qout[(size_t)(row0 + r) * DIM + lane * 4] = v;
        }
    }
}

// ======================= rescue reduce: merge 32 splits, finalize =======================

__global__ void vq_reduce2_k(const float* __restrict__ pv2, const int* __restrict__ pj2,
                             const int* __restrict__ list, const int* __restrict__ cnt,
                             const float* __restrict__ norms, const unsigned short* __restrict__ Bh,
                             float* __restrict__ qout, float* __restrict__ iout,
                             float* __restrict__ lout)
{
    __shared__ int rbuf[64], jb2[64];
    const int n = *cnt < CAP ? *cnt : CAP;
    const int i0 = blockIdx.x * 64;
    if (i0 >= n) return;
    const int tid = threadIdx.x;
    if (tid < 64) {
        int i = i0 + tid;
        float rl = 0.f;
        if (i < n) {
            float bv = pv2[i]; int bj = pj2[i];
#pragma unroll 4
            for (int s = 1; s < 32; ++s) {
                float v = pv2[(size_t)s * CAP + i];
                int   j = pj2[(size_t)s * CAP + i];
                if (v > bv || (v == bv && j < bj)) { bv = v; bj = j; }
            }
            int row = list[i];
            iout[row] = (float)bj;
            rbuf[tid] = row;
            jb2[tid]  = bj;
            rl = norms[row] - 2.0f * bv;
        } else {
            rbuf[tid] = -1;
        }
#pragma unroll
        for (int off = 32; off; off >>= 1) rl += __shfl_down(rl, off, 64);
        if (tid == 0) atomicAdd(lout, rl * LOSS_SCALE);
    }
    __syncthreads();
    const int lane = tid & 63;
    for (int r = tid >> 6; r < 64; r += 4) {
        int row = rbuf[r];
        if (row >= 0) {
            const _Float16* bp = (const _Float16*)Bh + (size_t)jb2[r] * BST + lane * 4;
            half4 h = *(const half4*)bp;
            half4 l = *(const half4*)(bp + 288);
            float4 v;
            v.x = (float)h[0] + (float)l[0];
            v.y = (float)h[1] + (float)l[1];
            v.z = (float)h[2] + (float)l[2];
            v.w = (float)h[3] + (float)l[3];
            *(float4*)&qout[(size_t)row * DIM + lane * 4] = v;
        }
    }
}

// ======================= fallback fp32 path (round-1, known-good) =======================

__global__ void transpose_k(const float* __restrict__ e, float* __restrict__ eT) {
    __shared__ float t[32][33];
    int jb = blockIdx.x * 32, db = blockIdx.y * 32;
#pragma unroll
    for (int i = 0; i < 4; ++i)
        t[threadIdx.y + i * 8][threadIdx.x] =
            e[(size_t)(db + threadIdx.y + i * 8) * NC + jb + threadIdx.x];
    __syncthreads();
#pragma unroll
    for (int i = 0; i < 4; ++i)
        eT[(size_t)(jb + threadIdx.y + i * 8) * DIM + db + threadIdx.x] =
            t[threadIdx.x][threadIdx.y + i * 8];
}

__global__ void row_norms_k(const float* __restrict__ x, float* __restrict__ norms) {
    int row  = blockIdx.x * 4 + (threadIdx.x >> 6);
    int lane = threadIdx.x & 63;
    const float4 v = ((const float4*)(x + (size_t)row * DIM))[lane];
    float s = v.x * v.x + v.y * v.y + v.z * v.z + v.w * v.w;
#pragma unroll
    for (int off = 32; off; off >>= 1) s += __shfl_down(s, off, 64);
    if (lane == 0) norms[row] = s;
}

__global__ void code_norms_fb_k(const float* __restrict__ e, float* __restrict__ cHalf) {
    int j = blockIdx.x * 256 + threadIdx.x;
    float s = 0.f;
    for (int d = 0; d < DIM; ++d) { float v = e[(size_t)d * NC + j]; s += v * v; }
    cHalf[j] = 0.5f * s;
}

__global__ __launch_bounds__(256, 4) void vq_main_k(
    const float* __restrict__ x, const float* __restrict__ e,
    const float* __restrict__ eT, const float* __restrict__ norms,
    const float* __restrict__ cHalf, float* __restrict__ qout,
    float* __restrict__ iout, float* __restrict__ lout, int useT)
{
    __shared__ float  As[2][32 * 68];
    __shared__ float4 Bs[2][512];
    const int tid  = threadIdx.x;
    const int row0 = blockIdx.x * 64;
    const int ty = tid >> 4, tx = tid & 15;
    const int ar = tid >> 2, ak = (tid & 3) * 4;
    const int bk = tid >> 4, bj = tid & 15;
    float bestv[4]; int bestj[4];
#pragma unroll
    for (int i = 0; i < 4; ++i) { bestv[i] = -3.4e38f; bestj[i] = 0; }
    float acc[4][4];
    float4 pa0, pa1, pb0, pb1;
    {
        const float* xp = x + (size_t)(row0 + ar) * DIM + ak;
        pa0 = *(const float4*)xp;
        pa1 = *(const float4*)(xp + 16);
        const float* ep = e + (size_t)bk * NC + bj * 4;
        pb0 = *(const float4*)ep;
        pb1 = *(const float4*)(ep + 16 * NC);
    }
    int buf = 0;
    for (int c = 0; c < 1024; ++c) {
        const int kc = c & 7;
#pragma unroll
        for (int q = 0; q < 4; ++q) As[buf][(ak + q) * 68 + ar]      = ((const float*)&pa0)[q];
#pragma unroll
        for (int q = 0; q < 4; ++q) As[buf][(16 + ak + q) * 68 + ar] = ((const float*)&pa1)[q];
        Bs[buf][bk * 16 + bj]        = pb0;
        Bs[buf][(bk + 16) * 16 + bj] = pb1;
        __syncthreads();
        if (c + 1 < 1024) {
            int j0n  = ((c + 1) >> 3) * 64;
            int kk0n = ((c + 1) & 7) * 32;
            const float* xp = x + (size_t)(row0 + ar) * DIM + kk0n + ak;
            pa0 = *(const float4*)xp;
            pa1 = *(const float4*)(xp + 16);
            const float* ep = e + (size_t)(kk0n + bk) * NC + j0n + bj * 4;
            pb0 = *(const float4*)ep;
            pb1 = *(const float4*)(ep + 16 * NC);
        }
        if (kc == 0) {
#pragma unroll
            for (int i = 0; i < 4; ++i)
#pragma unroll
                for (int j = 0; j < 4; ++j) acc[i][j] = 0.f;
        }
#pragma unroll
        for (int k = 0; k < 32; ++k) {
            float4 a = *(const float4*)&As[buf][k * 68 + ty * 4];
            float4 b = *(const float4*)&Bs[buf][k * 16 + tx];
            acc[0][0] += a.x * b.x; acc[0][1] += a.x * b.y; acc[0][2] += a.x * b.z; acc[0][3] += a.x * b.w;
            acc[1][0] += a.y * b.x; acc[1][1] += a.y * b.y; acc[1][2] += a.y * b.z; acc[1][3] += a.y * b.w;
            acc[2][0] += a.z * b.x; acc[2][1] += a.z * b.y; acc[2][2] += a.z * b.z; acc[2][3] += a.z * b.w;
            acc[3][0] += a.w * b.x; acc[3][1] += a.w * b.y; acc[3][2] += a.w * b.z; acc[3][3] += a.w * b.w;
        }
        if (kc == 7) {
            int j0 = (c >> 3) * 64;
            float4 ch = *(const float4*)&cHalf[j0 + tx * 4];
            int jb0 = j0 + tx * 4;
#pragma unroll
            for (int i = 0; i < 4; ++i)
#pragma unroll
                for (int j = 0; j < 4; ++j) {
                    float s = acc[i][j] - ((const float*)&ch)[j];
                    if (s > bestv[i]) { bestv[i] = s; bestj[i] = jb0 + j; }
                }
        }
        buf ^= 1;
    }
    __syncthreads();
    float* redv   = &As[0][0];
    int*   redj   = (int*)&As[0][1024];
    int*   idxbuf = (int*)&As[1][0];
#pragma unroll
    for (int i = 0; i < 4; ++i) {
        int r = ty * 4 + i;
        redv[r * 16 + tx] = bestv[i];
        redj[r * 16 + tx] = bestj[i];
    }
    __syncthreads();
    if (tid < 64) {
        float bvv = redv[tid * 16];
        int   bj2 = redj[tid * 16];
#pragma unroll
        for (int t = 1; t < 16; ++t) {
            float v = redv[tid * 16 + t];
            int   j = redj[tid * 16 + t];
            if (v > bvv || (v == bvv && j < bj2)) { bvv = v; bj2 = j; }
        }
        iout[row0 + tid] = (float)bj2;
        idxbuf[tid] = bj2;
        float rl = norms[row0 + tid] - 2.0f * bvv;
#pragma unroll
        for (int off = 32; off; off >>= 1) rl += __shfl_down(rl, off, 64);
        if (tid == 0) atomicAdd(lout, rl * LOSS_SCALE);
    }
    __syncthreads();
    {
        const int rr = tid >> 6, lane = tid & 63;
        for (int r = rr; r < 64; r += 4) {
            int j = idxbuf[r];
            float4 v;
            if (useT) {
                v = *(const float4*)&eT[(size_t)j * DIM + lane * 4];
            } else {
                int d = lane * 4;
                v.x = e[(size_t)d * NC + j];
                v.y = e[(size_t)(d + 1) * NC + j];
                v.z = e[(size_t)(d + 2) * NC + j];
                v.w = e[(size_t)(d + 3) * NC + j];
            }
            *(float4*)&qout[(size_t)(row0 + r) * DIM + lane * 4] = v;
        }
    }
}

// ======================= launch =======================

extern "C" void kernel_launch(void* const* d_in, const int* in_sizes, int n_in,
                              void* d_out, int out_size, void* d_ws, size_t ws_size,
                              hipStream_t stream) {
    const float* x = (const float*)d_in[0];   // [32768, 256]
    const float* e = (const float*)d_in[1];   // [256, 8192]

    float* qout = (float*)d_out;
    float* iout = qout + (size_t)NROW * DIM;
    float* lout = iout + NROW;

    char* ws = (char*)d_ws;
    const size_t offAh    = 0;                    // 32768*576*2 = 37,748,736
    const size_t offBh    = offAh + 37748736;     //  8192*576*2 =  9,437,184
    const size_t offNorms = offBh + 9437184;      //    131,072
    const size_t offCH    = offNorms + 131072;    //     32,768
    const size_t offPV    = offCH + 32768;        //    524,288
    const size_t offPJ    = offPV + 524288;       //    524,288
    const size_t offPSV   = offPJ + 524288;       //    524,288
    const size_t offPV2   = offPSV + 524288;      //  2,097,152
    const size_t offPJ2   = offPV2 + 2097152;     //  2,097,152
    const size_t offList  = offPJ2 + 2097152;     //     65,536
    const size_t offCnt   = offList + 65536;      //        256
    const size_t needFast = offCnt + 256;         // ~53.2 MB (proven: >=55.7 MB available)

    hipMemsetAsync(lout, 0, sizeof(float), stream);

    if (ws_size >= needFast) {
        unsigned short* Ah = (unsigned short*)(ws + offAh);
        unsigned short* Bh = (unsigned short*)(ws + offBh);
        float* norms = (float*)(ws + offNorms);
        float* cHalf = (float*)(ws + offCH);
        float* pv    = (float*)(ws + offPV);
        int*   pj    = (int*)(ws + offPJ);
        float* psv   = (float*)(ws + offPSV);
        float* pv2   = (float*)(ws + offPV2);
        int*   pj2   = (int*)(ws + offPJ2);
        int*   list  = (int*)(ws + offList);
        int*   cnt   = (int*)(ws + offCnt);

        hipMemsetAsync(cnt, 0, sizeof(int), stream);
        prep_a_k<<<NROW / 4, 256, 0, stream>>>(x, Ah, norms);
        code_norms_k<<<NC / 256, 256, 0, stream>>>(e, Bh, cHalf);
        prep_b_k<<<dim3(NC / 32, DIM / 32), dim3(32, 8), 0, stream>>>(e, Bh);
        // cheap pass: R15 (best-known, reverted verbatim)
        vq_cheap_k<<<1024, 512, 0, stream>>>(Ah, Bh, cHalf, pv, pj, psv);
        // merge + flag + finalize non-flagged
        vq_reduce_k<<<NROW / 64, 256, 0, stream>>>(
            pv, pj, psv, norms, Bh, qout, iout, lout, list, cnt);
        // precise pass (R19: 3-deep ring + counted vmcnt) on flagged rows
        vq_gemm_k<24, 2, 5, true><<<(CAP / 128) * 32, 256, 0, stream>>>(
            Ah, Bh, cHalf, pv2, pj2, nullptr, list, cnt);
        vq_reduce2_k<<<CAP / 64, 256, 0, stream>>>(
            pv2, pj2, list, cnt, norms, Bh, qout, iout, lout);
    } else {
        // round-1 fp32 fallback
        float* fws   = (float*)d_ws;
        float* norms = fws;
        float* cHalf = fws + NROW;
        float* eT    = fws + NROW + NC;
        size_t need_T = (size_t)(NROW + NC) * sizeof(float) + (size_t)NC * DIM * sizeof(float);
        int useT = (ws_size >= need_T) ? 1 : 0;
        row_norms_k<<<NROW / 4, 256, 0, stream>>>(x, norms);
        code_norms_fb_k<<<NC / 256, 256, 0, stream>>>(e, cHalf);
        if (useT)
            transpose_k<<<dim3(NC / 32, DIM / 32), dim3(32, 8), 0, stream>>>(e, eT);
        vq_main_k<<<NROW / 64, 256, 0, stream>>>(x, e, eT, norms, cHalf, qout, iout, lout, useT);
    }
}